// Round 4
// baseline (620.059 us; speedup 1.0000x reference)
//
#include <hip/hip_runtime.h>

// SparseAutoEncoder: hypernetwork-generated per-sample MLP weights, fused.
// EN layers (rows in en_W2): (2000,200) lin @0, (200,100) tanh @400200, (100,10) lin @420300
// DE layers (rows in de_W2): (10,100) lin @0, (100,200) tanh @1100, (200,2000) lin @21300
// Hyper width K = 64, batch B = 64. h: (b,k) b-major. xT layouts: (i,b) i-major.
//
// R4: fco_kernel output-blocks over O=8 neurons: the 16 lane-shared x floats
// (4 ds_read_b128, 48 LDS-cyc) now feed 128 fma (256 VALU-cyc) instead of 16
// (R3 was LDS-throughput-bound: 4 waves x 48 LDS-cyc > 32 VALU-cyc => 19% VALU).
// acc[8][16] in VGPRs (~128), W rows loaded per-lane from global (L1-served).

// ---------------------------------------------------------------------------
// prep: transpose z (64x2000) -> zT (2000x64), and compute h_en, h_de (64x64)
// ---------------------------------------------------------------------------
__global__ __launch_bounds__(256) void prep_kernel(
    const float* __restrict__ z, const float* __restrict__ mu,
    const float* __restrict__ enW0, const float* __restrict__ enb0,
    const float* __restrict__ enW1, const float* __restrict__ enb1,
    const float* __restrict__ deW0, const float* __restrict__ deb0,
    const float* __restrict__ deW1, const float* __restrict__ deb1,
    float* __restrict__ zT, float* __restrict__ hen, float* __restrict__ hde)
{
    __shared__ float tile[64 * 65];
    __shared__ float h0s[4][64];
    const int bid  = blockIdx.x;
    const int lane = threadIdx.x & 63;
    const int g    = threadIdx.x >> 6;

    if (bid < 32) {
        const int t0 = bid * 64;
        for (int bb = g; bb < 64; bb += 4) {
            int i = t0 + lane;
            tile[bb * 65 + lane] = (i < 2000) ? z[bb * 2000 + i] : 0.f;
        }
        __syncthreads();
        for (int ii = g; ii < 64; ii += 4) {
            int i = t0 + ii;
            if (i < 2000) zT[i * 64 + lane] = tile[lane * 65 + ii];
        }
    } else {
        const int task  = (bid - 32) * 4 + g;   // 0..127
        const int which = task >> 6;            // 0 = en, 1 = de
        const int b     = task & 63;
        const float* W0 = which ? deW0 : enW0;
        const float* b0 = which ? deb0 : enb0;
        const float* W1 = which ? deW1 : enW1;
        const float* b1 = which ? deb1 : enb1;
        float* hout     = which ? hde : hen;
        const int j = lane;
        float m0 = mu[b * 4 + 0], m1 = mu[b * 4 + 1], m2 = mu[b * 4 + 2], m3 = mu[b * 4 + 3];
        float v = tanhf(m0 * W0[j * 4 + 0] + m1 * W0[j * 4 + 1] +
                        m2 * W0[j * 4 + 2] + m3 * W0[j * 4 + 3] + b0[j]);
        h0s[g][j] = v;
        __syncthreads();
        float a = b1[j];
        const float* W1r = W1 + j * 64;
        #pragma unroll 8
        for (int k = 0; k < 64; ++k) a = fmaf(h0s[g][k], W1r[k], a);
        hout[b * 64 + j] = tanhf(a);
    }
}

// ---------------------------------------------------------------------------
// O-blocked fused hyper-FC layer (for big layers):
//   yT[o,b] = act( sum_k (T[o,b,k]+Wbias[o,k])*h[b,k] + sum_i x[b,i]*b2[o*NI+i]
//                  + b2[NO*NI+o] ),  T[o,b,k] = sum_i xT[i,b]*W2[(o*NI+i),k]
// lane = k; wave = batch-quarter; O output neurons per block (acc[O][16]).
// x chunk staged in LDS, broadcast via uniform ds_read_b128; W per-lane from
// global (L1 serves the 4-wave reuse). i split across NSPLIT blocks (atomics,
// linear layers only).
// ---------------------------------------------------------------------------
template <int NI, int NO, int O, int NSPLIT, bool TANH, bool ATOMIC>
__global__ __launch_bounds__(256) void fco_kernel(
    const float* __restrict__ xT,   // NI x 64 (i-major)
    const float* __restrict__ h,    // 64 x 64 (b-major)
    const float* __restrict__ W2,   // layer base, (NO*NI+NO) x 64
    const float* __restrict__ b2,   // layer base, NO*NI+NO
    float* __restrict__ yT)         // NO x 64
{
    constexpr int CH = NI / NSPLIT;          // NI divisible by NSPLIT
    __shared__ __align__(16) float xs[CH * 64];
    __shared__ float b2s[O][CH];
    __shared__ float xbs[O][64];
    const int lane = threadIdx.x & 63;
    const int wave = threadIdx.x >> 6;
    const int ot = blockIdx.x / NSPLIT;
    const int s  = blockIdx.x - ot * NSPLIT;
    const int o0 = ot * O;
    const int i0 = s * CH;

    // stage x chunk + O b2 rows into LDS
    {
        const float4* __restrict__ src = (const float4*)(xT + i0 * 64);
        float4* dst = (float4*)xs;
        for (int u = threadIdx.x; u < CH * 16; u += 256) dst[u] = src[u];
        for (int u = threadIdx.x; u < O * CH; u += 256) {
            int oo = u / CH, i = u - oo * CH;
            b2s[oo][i] = b2[(size_t)(o0 + oo) * NI + i0 + i];
        }
    }
    __syncthreads();

    const float* __restrict__ Wb = W2 + ((size_t)o0 * NI + i0) * 64 + lane;

    float acc[O][16];
    #pragma unroll
    for (int oo = 0; oo < O; ++oo)
        #pragma unroll
        for (int j = 0; j < 16; ++j) acc[oo][j] = 0.f;

    #pragma unroll 2
    for (int i = 0; i < CH; ++i) {
        float w[O];
        #pragma unroll
        for (int oo = 0; oo < O; ++oo)
            w[oo] = Wb[(size_t)oo * NI * 64 + (size_t)i * 64];   // sgpr-base + shared voffset
        const float4* xr = (const float4*)(xs + i * 64 + wave * 16);  // uniform -> broadcast
        float4 x0 = xr[0], x1 = xr[1], x2 = xr[2], x3 = xr[3];
        #pragma unroll
        for (int oo = 0; oo < O; ++oo) {
            acc[oo][ 0] = fmaf(x0.x, w[oo], acc[oo][ 0]);
            acc[oo][ 1] = fmaf(x0.y, w[oo], acc[oo][ 1]);
            acc[oo][ 2] = fmaf(x0.z, w[oo], acc[oo][ 2]);
            acc[oo][ 3] = fmaf(x0.w, w[oo], acc[oo][ 3]);
            acc[oo][ 4] = fmaf(x1.x, w[oo], acc[oo][ 4]);
            acc[oo][ 5] = fmaf(x1.y, w[oo], acc[oo][ 5]);
            acc[oo][ 6] = fmaf(x1.z, w[oo], acc[oo][ 6]);
            acc[oo][ 7] = fmaf(x1.w, w[oo], acc[oo][ 7]);
            acc[oo][ 8] = fmaf(x2.x, w[oo], acc[oo][ 8]);
            acc[oo][ 9] = fmaf(x2.y, w[oo], acc[oo][ 9]);
            acc[oo][10] = fmaf(x2.z, w[oo], acc[oo][10]);
            acc[oo][11] = fmaf(x2.w, w[oo], acc[oo][11]);
            acc[oo][12] = fmaf(x3.x, w[oo], acc[oo][12]);
            acc[oo][13] = fmaf(x3.y, w[oo], acc[oo][13]);
            acc[oo][14] = fmaf(x3.z, w[oo], acc[oo][14]);
            acc[oo][15] = fmaf(x3.w, w[oo], acc[oo][15]);
        }
    }

    // bias-dot epilogue: lane = b; wave w covers o' in {w, w+4, ...}
    constexpr int OPW = (O + 3) / 4;
    {
        float xbacc[OPW];
        #pragma unroll
        for (int u = 0; u < OPW; ++u) xbacc[u] = 0.f;
        #pragma unroll 4
        for (int i = 0; i < CH; ++i) {
            float xv = xs[i * 64 + lane];
            #pragma unroll
            for (int u = 0; u < OPW; ++u) {
                int oo = wave + 4 * u;
                if (oo < O) xbacc[u] = fmaf(xv, b2s[oo][i], xbacc[u]);
            }
        }
        #pragma unroll
        for (int u = 0; u < OPW; ++u) {
            int oo = wave + 4 * u;
            if (oo < O) xbs[oo][lane] = xbacc[u];
        }
    }
    __syncthreads();

    // k-contraction with h; butterfly over 64 lanes per (oo, b)
    float wb[O];
    #pragma unroll
    for (int oo = 0; oo < O; ++oo)
        wb[oo] = (!ATOMIC || s == 0) ? W2[((size_t)NO * NI + o0 + oo) * 64 + lane] : 0.f;

    float myv[O];
    #pragma unroll
    for (int oo = 0; oo < O; ++oo) myv[oo] = 0.f;
    #pragma unroll
    for (int j = 0; j < 16; ++j) {
        int b = wave * 16 + j;
        float hv = h[b * 64 + lane];
        #pragma unroll
        for (int oo = 0; oo < O; ++oo) {
            float v = (acc[oo][j] + wb[oo]) * hv;
            #pragma unroll
            for (int m = 32; m >= 1; m >>= 1) v += __shfl_xor(v, m, 64);
            if (lane == j) myv[oo] = v;
        }
    }
    if (lane < 16) {
        int b = wave * 16 + lane;
        #pragma unroll
        for (int oo = 0; oo < O; ++oo) {
            float out = myv[oo] + xbs[oo][b];
            if (!ATOMIC || s == 0) out += b2[(size_t)NO * NI + o0 + oo];
            if (TANH) out = tanhf(out);
            if (ATOMIC) atomicAdd(&yT[(o0 + oo) * 64 + b], out);
            else        yT[(o0 + oo) * 64 + b] = out;
        }
    }
}

// ---------------------------------------------------------------------------
// original fc_kernel (kept for small/mid layers)
// ---------------------------------------------------------------------------
template <int NI, int NO, int NSPLIT, bool TANH, bool ATOMIC>
__global__ __launch_bounds__(256) void fc_kernel(
    const float* __restrict__ xT, const float* __restrict__ h,
    const float* __restrict__ W2, const float* __restrict__ b2,
    float* __restrict__ yT)
{
    constexpr int CH = NI / NSPLIT;
    __shared__ __align__(16) float xs[CH * 64];
    __shared__ float b2s[CH];
    __shared__ float xbs[64];
    const int lane = threadIdx.x & 63;
    const int wave = threadIdx.x >> 6;
    const int o = blockIdx.x / NSPLIT;
    const int s = blockIdx.x - o * NSPLIT;
    const int i0 = s * CH;

    {
        const float4* __restrict__ src = (const float4*)(xT + i0 * 64);
        float4* dst = (float4*)xs;
        for (int u = threadIdx.x; u < CH * 16; u += 256) dst[u] = src[u];
        const float* __restrict__ bsrc = b2 + (size_t)o * NI + i0;
        for (int u = threadIdx.x; u < CH; u += 256) b2s[u] = bsrc[u];
    }
    __syncthreads();

    const float* __restrict__ Wp = W2 + ((size_t)o * NI + i0) * 64 + lane;

    float acc[16];
    #pragma unroll
    for (int j = 0; j < 16; ++j) acc[j] = 0.f;
    float xb_acc = 0.f;

    #pragma unroll 4
    for (int i = 0; i < CH; ++i) {
        float w = Wp[(size_t)i * 64];
        if (wave == 0)
            xb_acc = fmaf(xs[i * 64 + lane], b2s[i], xb_acc);
        const float4* xr = (const float4*)(xs + i * 64 + wave * 16);
        float4 x0 = xr[0], x1 = xr[1], x2 = xr[2], x3 = xr[3];
        acc[ 0] = fmaf(x0.x, w, acc[ 0]);
        acc[ 1] = fmaf(x0.y, w, acc[ 1]);
        acc[ 2] = fmaf(x0.z, w, acc[ 2]);
        acc[ 3] = fmaf(x0.w, w, acc[ 3]);
        acc[ 4] = fmaf(x1.x, w, acc[ 4]);
        acc[ 5] = fmaf(x1.y, w, acc[ 5]);
        acc[ 6] = fmaf(x1.z, w, acc[ 6]);
        acc[ 7] = fmaf(x1.w, w, acc[ 7]);
        acc[ 8] = fmaf(x2.x, w, acc[ 8]);
        acc[ 9] = fmaf(x2.y, w, acc[ 9]);
        acc[10] = fmaf(x2.z, w, acc[10]);
        acc[11] = fmaf(x2.w, w, acc[11]);
        acc[12] = fmaf(x3.x, w, acc[12]);
        acc[13] = fmaf(x3.y, w, acc[13]);
        acc[14] = fmaf(x3.z, w, acc[14]);
        acc[15] = fmaf(x3.w, w, acc[15]);
    }

    if (wave == 0) xbs[lane] = xb_acc;

    float wb = 0.f;
    if (!ATOMIC || s == 0) wb = W2[((size_t)NO * NI + o) * 64 + lane];
    float myv = 0.f;
    #pragma unroll
    for (int j = 0; j < 16; ++j) {
        int b = wave * 16 + j;
        float v = (acc[j] + wb) * h[b * 64 + lane];
        #pragma unroll
        for (int m = 32; m >= 1; m >>= 1) v += __shfl_xor(v, m, 64);
        if (lane == j) myv = v;
    }
    __syncthreads();
    if (lane < 16) {
        int b = wave * 16 + lane;
        float out = myv + xbs[b];
        if (!ATOMIC || s == 0) out += b2[(size_t)NO * NI + o];
        if (TANH) out = tanhf(out);
        if (ATOMIC) atomicAdd(&yT[o * 64 + b], out);
        else        yT[o * 64 + b] = out;
    }
}

// ---------------------------------------------------------------------------
// finalize: d_out = [ z_reconst (64x2000 b-major) , x_enc (64x10 b-major) ]
// ---------------------------------------------------------------------------
__global__ __launch_bounds__(256) void final_kernel(
    const float* __restrict__ d3,   // 2000 x 64 (o-major)
    const float* __restrict__ y3,   // 10 x 64 (o-major)
    float* __restrict__ out)
{
    int t = blockIdx.x * 256 + threadIdx.x;
    if (t < 128000) {
        int b = t / 2000, oo = t - b * 2000;
        out[t] = d3[oo * 64 + b];
    } else if (t < 128640) {
        int u = t - 128000;
        int b = u / 10, oo = u - b * 10;
        out[t] = y3[oo * 64 + b];
    }
}

extern "C" void kernel_launch(void* const* d_in, const int* in_sizes, int n_in,
                              void* d_out, int out_size, void* d_ws, size_t ws_size,
                              hipStream_t stream)
{
    const float* z    = (const float*)d_in[0];
    const float* mu   = (const float*)d_in[1];
    const float* enW0 = (const float*)d_in[2];
    const float* enb0 = (const float*)d_in[3];
    const float* enW1 = (const float*)d_in[4];
    const float* enb1 = (const float*)d_in[5];
    const float* enW2 = (const float*)d_in[6];
    const float* enb2 = (const float*)d_in[7];
    const float* deW0 = (const float*)d_in[8];
    const float* deb0 = (const float*)d_in[9];
    const float* deW1 = (const float*)d_in[10];
    const float* deb1 = (const float*)d_in[11];
    const float* deW2 = (const float*)d_in[12];
    const float* deb2 = (const float*)d_in[13];

    float* ws  = (float*)d_ws;
    float* zT  = ws;                 // 2000*64
    float* hen = zT + 128000;        // 64*64
    float* hde = hen + 4096;         // 64*64
    float* y1  = hde + 4096;         // 200*64  (atomic target -> zeroed)
    float* y2  = y1 + 200 * 64;      // 100*64
    float* y3  = y2 + 100 * 64;      // 10*64   (x_enc, transposed)
    float* d1  = y3 + 10 * 64;       // 100*64
    float* d2  = d1 + 100 * 64;      // 200*64
    float* d3  = d2 + 200 * 64;      // 2000*64 (atomic target -> zeroed)
    float* out = (float*)d_out;

    hipMemsetAsync(y1, 0, 200 * 64 * sizeof(float), stream);
    hipMemsetAsync(d3, 0, 2000 * 64 * sizeof(float), stream);
    prep_kernel<<<64, 256, 0, stream>>>(z, mu, enW0, enb0, enW1, enb1,
                                        deW0, deb0, deW1, deb1, zT, hen, hde);
    // encoder
    fco_kernel<2000, 200, 8, 20, false, true ><<<500, 256, 0, stream>>>(zT, hen, enW2, enb2, y1);
    fc_kernel < 200, 100,     1, true,  false><<<100, 256, 0, stream>>>(y1, hen, enW2 + (size_t)400200 * 64, enb2 + 400200, y2);
    fc_kernel < 100,  10,     1, false, false><<< 10, 256, 0, stream>>>(y2, hen, enW2 + (size_t)420300 * 64, enb2 + 420300, y3);
    // decoder
    fc_kernel <  10, 100,     1, false, false><<<100, 256, 0, stream>>>(y3, hde, deW2, deb2, d1);
    fc_kernel < 100, 200,     1, true,  false><<<200, 256, 0, stream>>>(d1, hde, deW2 + (size_t)1100 * 64, deb2 + 1100, d2);
    fco_kernel< 200, 2000, 8, 2, false, true ><<<500, 256, 0, stream>>>(d2, hde, deW2 + (size_t)21300 * 64, deb2 + 21300, d3);

    final_kernel<<<(128640 + 255) / 256, 256, 0, stream>>>(d3, y3, out);
}